// Round 3
// baseline (4890.443 us; speedup 1.0000x reference)
//
#include <hip/hip_runtime.h>
#include <hip/hip_fp16.h>
#include <stdint.h>

#define TT 2048
#define BB 16
#define DD 1024
static const size_t H0OFF = 33554432; // 2048*16*1024 floats (start of h section in d_out)

typedef _Float16 f16;
typedef _Float16 f16x2 __attribute__((ext_vector_type(2)));
typedef _Float16 f16x8 __attribute__((ext_vector_type(8)));
typedef float f32x4 __attribute__((ext_vector_type(4)));

// ---------------- threefry + normal (replicates jax.random.normal(key(1),(1024,),f32)) ----
__device__ __forceinline__ float erfinv_xla(float x) {
  float w = -log1pf(-x * x);
  float p;
  if (w < 5.0f) {
    w -= 2.5f;
    p = 2.81022636e-08f;
    p = fmaf(p, w, 3.43273939e-07f);
    p = fmaf(p, w, -3.5233877e-06f);
    p = fmaf(p, w, -4.39150654e-06f);
    p = fmaf(p, w, 0.00021858087f);
    p = fmaf(p, w, -0.00125372503f);
    p = fmaf(p, w, -0.00417768164f);
    p = fmaf(p, w, 0.246640727f);
    p = fmaf(p, w, 1.50140941f);
  } else {
    w = sqrtf(w) - 3.0f;
    p = -0.000200214257f;
    p = fmaf(p, w, 0.000100950558f);
    p = fmaf(p, w, 0.00134934322f);
    p = fmaf(p, w, -0.00367342844f);
    p = fmaf(p, w, 0.00573950773f);
    p = fmaf(p, w, -0.0076224613f);
    p = fmaf(p, w, 0.00943887047f);
    p = fmaf(p, w, 1.00167406f);
    p = fmaf(p, w, 2.83297682f);
  }
  return p * x;
}

__device__ __forceinline__ float bits_to_normal(unsigned bits) {
  unsigned fb = (bits >> 9) | 0x3f800000u;
  float f = __uint_as_float(fb) - 1.0f;          // [0,1)
  const float lo = -0.99999994f;                 // nextafterf(-1,0)
  float u = f * 2.0f + lo;
  u = fmaxf(lo, u);
  return __uint_as_float(0x3fb504f3u) * erfinv_xla(u); // sqrt(2) fp32
}

#define TF_ROUND(r) { x0 += x1; x1 = (x1 << r) | (x1 >> (32 - r)); x1 ^= x0; }

__global__ void k_u0(float* t0, float* u) {
  __shared__ float red[512];
  int i = threadIdx.x; // 512 threads
  unsigned ks0 = 0u, ks1 = 1u, ks2 = 0x1BD11BDAu ^ 0u ^ 1u;
  unsigned x0 = (unsigned)i + ks0;
  unsigned x1 = (unsigned)(i + 512) + ks1;
  TF_ROUND(13) TF_ROUND(15) TF_ROUND(26) TF_ROUND(6)
  x0 += ks1; x1 += ks2 + 1u;
  TF_ROUND(17) TF_ROUND(29) TF_ROUND(16) TF_ROUND(24)
  x0 += ks2; x1 += ks0 + 2u;
  TF_ROUND(13) TF_ROUND(15) TF_ROUND(26) TF_ROUND(6)
  x0 += ks0; x1 += ks1 + 3u;
  TF_ROUND(17) TF_ROUND(29) TF_ROUND(16) TF_ROUND(24)
  x0 += ks1; x1 += ks2 + 4u;
  TF_ROUND(13) TF_ROUND(15) TF_ROUND(26) TF_ROUND(6)
  x0 += ks2; x1 += ks0 + 5u;
  float z0 = bits_to_normal(x0);
  float z1 = bits_to_normal(x1);
  t0[i] = z0; t0[i + 512] = z1;
  red[i] = z0 * z0 + z1 * z1;
  __syncthreads();
  for (int s = 256; s > 0; s >>= 1) { if (i < s) red[i] += red[i + s]; __syncthreads(); }
  float inv = 1.0f / sqrtf(red[0]);
  u[i] = t0[i] * inv; u[i + 512] = t0[i + 512] * inv;
}

// ---------------- power iteration helpers ----------------
__global__ void k_mvT(const float* __restrict__ W, const float* __restrict__ u,
                      float* __restrict__ out) { // out[j] = sum_i W[i,j]*u[i]
  int j = blockIdx.x * 256 + threadIdx.x;
  float acc = 0.f;
  for (int i = 0; i < DD; ++i) acc = fmaf(W[(size_t)i * DD + j], u[i], acc);
  out[j] = acc;
}

__global__ void k_mv(const float* __restrict__ W, const float* __restrict__ v,
                     float* __restrict__ out) { // out[i] = sum_j W[i,j]*v[j]
  int gtid = blockIdx.x * 256 + threadIdx.x;
  int wave = gtid >> 6, lane = threadIdx.x & 63;
  for (int rr = 0; rr < 16; ++rr) {
    int row = wave * 16 + rr;
    float acc = 0.f;
    for (int c = 0; c < 16; ++c) {
      int col = c * 64 + lane;
      acc = fmaf(W[(size_t)row * DD + col], v[col], acc);
    }
    for (int off = 32; off > 0; off >>= 1) acc += __shfl_down(acc, off, 64);
    if (lane == 0) out[row] = acc;
  }
}

__global__ void k_norm(const float* __restrict__ src, float* __restrict__ dst, float eps) {
  __shared__ float red[1024];
  int i = threadIdx.x;
  float xv = src[i];
  red[i] = xv * xv;
  __syncthreads();
  for (int s = 512; s > 0; s >>= 1) { if (i < s) red[i] += red[i + s]; __syncthreads(); }
  float inv = 1.0f / (sqrtf(red[0]) + eps);
  dst[i] = src[i] * inv;
}

__global__ void k_sigma(const float* __restrict__ u, const float* __restrict__ wv,
                        float* __restrict__ scale) {
  __shared__ float red[1024];
  int i = threadIdx.x;
  red[i] = u[i] * wv[i];
  __syncthreads();
  for (int s = 512; s > 0; s >>= 1) { if (i < s) red[i] += red[i + s]; __syncthreads(); }
  if (i == 0) scale[0] = 0.99f / (fabsf(red[0]) + 1e-8f);
}

__global__ void k_castWh(const float* __restrict__ Wh, const float* __restrict__ scale,
                         f16* __restrict__ WhH) {
  int i = blockIdx.x * 256 + threadIdx.x;
  float s = scale[0];
  WhH[i] = (f16)(Wh[i] * s);
}

// ---------------- batched GEMM: C[m,e] = sum_d X[m,d]*W[e,d] + bias[e] (W in f32) ------
__global__ __launch_bounds__(256) void k_gemm(const float* __restrict__ X,
                                              const float* __restrict__ Wt,
                                              const float* __restrict__ bias,
                                              float* __restrict__ Cout) {
  __shared__ __align__(16) f16 Ah[128 * 64];
  __shared__ __align__(16) f16 Bh[128 * 64];
  int m0 = blockIdx.x * 128, n0 = blockIdx.y * 128;
  int tid = threadIdx.x, lane = tid & 63, w = tid >> 6;
  int wm = w & 1, wn = w >> 1;
  int srow = tid >> 3, scol = (tid & 7) * 8;
  f32x4 acc[4][4];
#pragma unroll
  for (int i = 0; i < 4; ++i)
#pragma unroll
    for (int j = 0; j < 4; ++j) acc[i][j] = (f32x4){0.f, 0.f, 0.f, 0.f};

  for (int kt = 0; kt < 16; ++kt) {
    int k0 = kt * 64;
#pragma unroll
    for (int c = 0; c < 4; ++c) {
      int row = c * 32 + srow;
      const float4* sa = (const float4*)(X + (size_t)(m0 + row) * DD + k0 + scol);
      float4 a0 = sa[0], a1 = sa[1];
      f16x8 hv;
      hv[0] = (f16)a0.x; hv[1] = (f16)a0.y; hv[2] = (f16)a0.z; hv[3] = (f16)a0.w;
      hv[4] = (f16)a1.x; hv[5] = (f16)a1.y; hv[6] = (f16)a1.z; hv[7] = (f16)a1.w;
      *(f16x8*)&Ah[row * 64 + scol] = hv;
      const float4* sb = (const float4*)(Wt + (size_t)(n0 + row) * DD + k0 + scol);
      float4 b0 = sb[0], b1 = sb[1];
      f16x8 hw;
      hw[0] = (f16)b0.x; hw[1] = (f16)b0.y; hw[2] = (f16)b0.z; hw[3] = (f16)b0.w;
      hw[4] = (f16)b1.x; hw[5] = (f16)b1.y; hw[6] = (f16)b1.z; hw[7] = (f16)b1.w;
      *(f16x8*)&Bh[row * 64 + scol] = hw;
    }
    __syncthreads();
#pragma unroll
    for (int ks = 0; ks < 2; ++ks) {
      f16x8 af[4], bf[4];
#pragma unroll
      for (int i = 0; i < 4; ++i)
        af[i] = *(const f16x8*)&Ah[(wm * 64 + i * 16 + (lane & 15)) * 64 + ks * 32 + (lane >> 4) * 8];
#pragma unroll
      for (int j = 0; j < 4; ++j)
        bf[j] = *(const f16x8*)&Bh[(wn * 64 + j * 16 + (lane & 15)) * 64 + ks * 32 + (lane >> 4) * 8];
#pragma unroll
      for (int i = 0; i < 4; ++i)
#pragma unroll
        for (int j = 0; j < 4; ++j)
          acc[i][j] = __builtin_amdgcn_mfma_f32_16x16x32_f16(af[i], bf[j], acc[i][j], 0, 0, 0);
    }
    __syncthreads();
  }
#pragma unroll
  for (int j = 0; j < 4; ++j) {
    int col = n0 + wn * 64 + j * 16 + (lane & 15);
    float bs = bias[col];
#pragma unroll
    for (int i = 0; i < 4; ++i) {
      int rbase = m0 + wm * 64 + i * 16 + (lane >> 4) * 4;
#pragma unroll
      for (int r = 0; r < 4; ++r)
        Cout[(size_t)(rbase + r) * DD + col] = acc[i][j][r] + bs;
    }
  }
}

// ---------------- persistent recurrence (wave-autonomous tagged exchange) ----------------
__device__ __forceinline__ float fdot2u(uint32_t a, uint32_t b, float c) {
#if __has_builtin(__builtin_amdgcn_fdot2)
  return __builtin_amdgcn_fdot2(__builtin_bit_cast(f16x2, a),
                                __builtin_bit_cast(f16x2, b), c, false);
#else
  f16x2 av = __builtin_bit_cast(f16x2, a), bv = __builtin_bit_cast(f16x2, b);
  return c + (float)av[0] * (float)bv[0] + (float)av[1] * (float)bv[1];
#endif
}

__device__ __forceinline__ float sigmoid_fast(float v) {
  return 1.0f / (1.0f + __expf(-v));
}
__device__ __forceinline__ float tanh_fast(float v) {
  float t = __expf(-2.0f * fabsf(v));
  float r = (1.0f - t) / (1.0f + t);
  return copysignf(r, v);
}

__global__ __launch_bounds__(256, 1) void k_rec(const float* __restrict__ x,
                                                const float* __restrict__ h0,
                                                const float* __restrict__ b_gate,
                                                const f16* __restrict__ WhH,
                                                uint32_t* __restrict__ hx,
                                                float* __restrict__ d_out) {
  int bid = blockIdx.x;
  int batch = bid & 15;          // batch-mates land on one XCD under round-robin (perf only)
  int eslice = bid >> 4;         // 0..15 : this block produces rows [64*eslice, 64*eslice+64)
  int tid = threadIdx.x, lane = tid & 63, wv = tid >> 6;

  __shared__ __align__(16) uint16_t hsh[1024];      // h_t as f16; wave w owns [256w,256w+256)
  __shared__ float partial[2][4][64];               // [parity][d-chunk][block-row]

  // W_h_eff: lane owns block-row `lane` (global row 64*eslice+lane), d-chunk wv (256 cols)
  uint4 wq[32];
  {
    const uint4* wp = (const uint4*)(WhH + (size_t)(64 * eslice + lane) * DD + 256 * wv);
#pragma unroll
    for (int k = 0; k < 32; ++k) wq[k] = wp[k];
  }

  // stage h0 into this wave's LDS region
#pragma unroll
  for (int k = 0; k < 4; ++k) {
    int g = 256 * wv + 64 * k + lane;
    hsh[g] = __builtin_bit_cast(uint16_t, (f16)h0[(size_t)batch * DD + g]);
  }

  // tail state (lanes 0..15 of each wave): block-row rr = 16*wv + lane
  float h_own = 0.f, bgv = 0.f, cx_c = 0.f, dr_c = 0.f, xv_c = 0.f;
  int e_g = 0;
  if (lane < 16) {
    int rr = 16 * wv + lane;
    e_g = 64 * eslice + rr;
    size_t b0 = (size_t)batch * DD + e_g;
    h_own = h0[b0];
    bgv = b_gate[e_g];
    d_out[H0OFF + b0] = h_own;        // h[0]
    cx_c = d_out[b0];                 // cand_x[0]
    dr_c = d_out[H0OFF + 16384 + b0]; // delta_raw[0]
    xv_c = x[b0];
  }
  asm volatile("s_waitcnt lgkmcnt(0)" ::: "memory");

#pragma unroll 1
  for (int t = 0; t < TT; ++t) {
    // prefetch next step's streams (one iteration of slack before use)
    float cx_n = 0.f, dr_n = 0.f, xv_n = 0.f;
    if (lane < 16 && t + 1 < TT) {
      size_t bn = (size_t)(t + 1) * 16384 + (size_t)batch * DD + e_g;
      cx_n = d_out[bn];
      dr_n = d_out[H0OFF + 16384 + bn];
      xv_n = x[bn];
    }

    // matvec over this wave's d-chunk: 4 independent acc chains (issue-bound, not dep-bound)
    const uint4* hq = (const uint4*)hsh;
    float a0 = 0.f, a1 = 0.f, a2 = 0.f, a3 = 0.f;
#pragma unroll
    for (int k = 0; k < 32; k += 4) {
      {
        uint4 q = hq[32 * wv + k + 0]; uint4 wqq = wq[k + 0];
        a0 = fdot2u(wqq.x, q.x, a0); a0 = fdot2u(wqq.y, q.y, a0);
        a0 = fdot2u(wqq.z, q.z, a0); a0 = fdot2u(wqq.w, q.w, a0);
      }
      {
        uint4 q = hq[32 * wv + k + 1]; uint4 wqq = wq[k + 1];
        a1 = fdot2u(wqq.x, q.x, a1); a1 = fdot2u(wqq.y, q.y, a1);
        a1 = fdot2u(wqq.z, q.z, a1); a1 = fdot2u(wqq.w, q.w, a1);
      }
      {
        uint4 q = hq[32 * wv + k + 2]; uint4 wqq = wq[k + 2];
        a2 = fdot2u(wqq.x, q.x, a2); a2 = fdot2u(wqq.y, q.y, a2);
        a2 = fdot2u(wqq.z, q.z, a2); a2 = fdot2u(wqq.w, q.w, a2);
      }
      {
        uint4 q = hq[32 * wv + k + 3]; uint4 wqq = wq[k + 3];
        a3 = fdot2u(wqq.x, q.x, a3); a3 = fdot2u(wqq.y, q.y, a3);
        a3 = fdot2u(wqq.z, q.z, a3); a3 = fdot2u(wqq.w, q.w, a3);
      }
    }
    partial[t & 1][wv][lane] = (a0 + a1) + (a2 + a3);
    __syncthreads();                                   // the ONE barrier per step

    uint32_t want = (uint32_t)(t + 1);
    uint32_t* sl = hx + (size_t)(want & 15u) * (BB * DD) + (size_t)batch * DD;

    // tail: each wave finishes its 16 rows (lanes 0..15)
    if (lane < 16) {
      int rr = 16 * wv + lane;
      const float* pp = &partial[t & 1][0][rr];
      float hdot = (pp[0] + pp[64]) + (pp[128] + pp[192]);
      float dlt = sigmoid_fast(dr_c);
      float cand = tanh_fast(cx_c + hdot);
      float hn = (1.f - dlt) * h_own + dlt * cand;
      // critical path first: publish tagged h
      uint16_t hb = __builtin_bit_cast(uint16_t, (f16)hn);
      __hip_atomic_store(&sl[e_g], (want << 16) | (uint32_t)hb,
                         __ATOMIC_RELAXED, __HIP_MEMORY_SCOPE_AGENT);
      size_t base = (size_t)t * 16384 + (size_t)batch * DD + e_g;
      float z = hn + xv_c + bgv;
      d_out[base] = hn * z * sigmoid_fast(z);   // out[t]   (overwrites consumed cand_x[t])
      d_out[H0OFF + 16384 + base] = hn;         // h[t+1]   (overwrites consumed delta_raw[t])
      h_own = hn; cx_c = cx_n; dr_c = dr_n; xv_c = xv_n;
    }

    if (t + 1 < TT) {
      // hierarchical spin: 16 sentinel words = first element of each producer wave-group
      int sidx = 256 * wv + 64 * (lane >> 2) + 16 * (lane & 3);
      while (true) {
        uint32_t swd = (lane < 16)
            ? __hip_atomic_load(&sl[sidx], __ATOMIC_RELAXED, __HIP_MEMORY_SCOPE_AGENT)
            : (want << 16);
        if (__all((swd >> 16) == want)) break;
        __builtin_amdgcn_s_sleep(1);
      }
      // bulk load this wave's 256 tagged words; validate embedded tags (self-validating)
      uint32_t v0, v1, v2, v3;
      while (true) {
        v0 = __hip_atomic_load(&sl[256 * wv + lane],       __ATOMIC_RELAXED, __HIP_MEMORY_SCOPE_AGENT);
        v1 = __hip_atomic_load(&sl[256 * wv + 64 + lane],  __ATOMIC_RELAXED, __HIP_MEMORY_SCOPE_AGENT);
        v2 = __hip_atomic_load(&sl[256 * wv + 128 + lane], __ATOMIC_RELAXED, __HIP_MEMORY_SCOPE_AGENT);
        v3 = __hip_atomic_load(&sl[256 * wv + 192 + lane], __ATOMIC_RELAXED, __HIP_MEMORY_SCOPE_AGENT);
        bool ok = ((v0 >> 16) == want) & ((v1 >> 16) == want) &
                  ((v2 >> 16) == want) & ((v3 >> 16) == want);
        if (__all(ok)) break;
        __builtin_amdgcn_s_sleep(1);
      }
      // stage into this wave's own LDS region (wave-local visibility: lgkmcnt only)
      hsh[256 * wv + lane]       = (uint16_t)v0;
      hsh[256 * wv + 64 + lane]  = (uint16_t)v1;
      hsh[256 * wv + 128 + lane] = (uint16_t)v2;
      hsh[256 * wv + 192 + lane] = (uint16_t)v3;
      asm volatile("s_waitcnt lgkmcnt(0)" ::: "memory");
    }
  }
}

// ---------------- launch ----------------
extern "C" void kernel_launch(void* const* d_in, const int* in_sizes, int n_in,
                              void* d_out_v, int out_size, void* d_ws, size_t ws_size,
                              hipStream_t stream) {
  const float* x  = (const float*)d_in[0];
  const float* h0 = (const float*)d_in[1];
  const float* Wx = (const float*)d_in[2];
  const float* Wh = (const float*)d_in[3];
  const float* Wd = (const float*)d_in[4];
  const float* b  = (const float*)d_in[5];
  const float* bd = (const float*)d_in[6];
  const float* bg = (const float*)d_in[7];
  float* out = (float*)d_out_v;

  char* ws = (char*)d_ws;
  float* u    = (float*)(ws + 0);
  float* v    = (float*)(ws + 4096);
  float* t0   = (float*)(ws + 8192);
  float* sc   = (float*)(ws + 12288);
  uint32_t* hx = (uint32_t*)(ws + 65536);        // 16 slots * 16 batches * 1024 words = 1 MiB
  f16* WhH  = (f16*)(ws + 2097152);              // 2 MiB

  hipMemsetAsync(hx, 0, (size_t)16 * BB * DD * 4, stream);  // clear ring tags (replay safety)

  k_u0<<<1, 512, 0, stream>>>(t0, u);
  for (int it = 0; it < 3; ++it) {
    k_mvT<<<4, 256, 0, stream>>>(Wh, u, t0);
    k_norm<<<1, 1024, 0, stream>>>(t0, v, 1e-8f);
    k_mv<<<16, 256, 0, stream>>>(Wh, v, t0);
    k_norm<<<1, 1024, 0, stream>>>(t0, u, 1e-8f);
  }
  k_sigma<<<1, 1024, 0, stream>>>(u, t0, sc);
  k_castWh<<<4096, 256, 0, stream>>>(Wh, sc, WhH);

  dim3 gg(256, 8, 1);
  k_gemm<<<gg, 256, 0, stream>>>(x, Wx, b, out);                   // cand_x -> out region
  k_gemm<<<gg, 256, 0, stream>>>(x, Wd, bd, out + H0OFF + 16384);  // delta_raw -> h region (+1 slot)

  k_rec<<<256, 256, 0, stream>>>(x, h0, bg, WhH, hx, out);
}